// Round 10
// baseline (327.529 us; speedup 1.0000x reference)
//
#include <hip/hip_runtime.h>
#include <hip/hip_bf16.h>
#include <math.h>

// (B,S,D,H) = (2,2048,1024,16), DK=64
#define B_ 2
#define S_ 2048
#define D_ 1024
#define H_ 16
#define DK_ 64

#define ROPE_C 0.4152410118609203f   // log2(10000)/32
#define LOG2E 1.4426950408889634f

typedef float f4 __attribute__((ext_vector_type(4)));
typedef short s8 __attribute__((ext_vector_type(8)));

__device__ __forceinline__ ushort f2b(float f) {
  union { float f; uint u; } v; v.f = f;
  uint u = v.u + 0x7fffu + ((v.u >> 16) & 1u);
  return (ushort)(u >> 16);
}

__device__ __forceinline__ float b2f(ushort u) {
  union { uint u; float f; } v; v.u = ((uint)u) << 16;
  return v.f;
}

// async global->LDS DMA, 16 B per lane. LDS dest = wave-uniform base + lane*16.
__device__ __forceinline__ void async16(const ushort* g, ushort* l) {
  __builtin_amdgcn_global_load_lds(
      (const __attribute__((address_space(1))) uint*)g,
      (__attribute__((address_space(3))) uint*)l, 16, 0, 0);
}

// ---------------------------------------------------------------------------
// Prep 1: fp32 -> bf16 flat convert, all three X tensors in one launch.
// Grid 6144: 2048 blocks per tensor. 8 elems/thread.
// ---------------------------------------------------------------------------
__global__ __launch_bounds__(256) void conv_x3(
    const float* __restrict__ ia, const float* __restrict__ ib,
    const float* __restrict__ ic,
    ushort* __restrict__ oa, ushort* __restrict__ ob, ushort* __restrict__ oc) {
  const int bid = blockIdx.x;
  const int which = bid >> 11;
  const float* in = (which == 0) ? ia : (which == 1) ? ib : ic;
  ushort* out = (which == 0) ? oa : (which == 1) ? ob : oc;
  int idx = ((bid & 2047) * 256 + threadIdx.x) * 8;
  float4 a = *(const float4*)&in[idx];
  float4 b = *(const float4*)&in[idx + 4];
  ushort tmp[8] = {f2b(a.x), f2b(a.y), f2b(a.z), f2b(a.w),
                   f2b(b.x), f2b(b.y), f2b(b.z), f2b(b.w)};
  *(uint4*)&out[idx] = *(uint4*)tmp;
}

// ---------------------------------------------------------------------------
// Prep 2: all four W fp32 [K][N] -> Wt bf16 [N][K] in one launch (z = tensor).
// ---------------------------------------------------------------------------
__global__ __launch_bounds__(256) void transpose_w4(
    const float* __restrict__ w0, const float* __restrict__ w1,
    const float* __restrict__ w2, const float* __restrict__ w3,
    ushort* __restrict__ o0, ushort* __restrict__ o1,
    ushort* __restrict__ o2, ushort* __restrict__ o3) {
  __shared__ ushort T[64][65];
  const int z = blockIdx.z;
  const float* W = (z == 0) ? w0 : (z == 1) ? w1 : (z == 2) ? w2 : w3;
  ushort* Wt = (z == 0) ? o0 : (z == 1) ? o1 : (z == 2) ? o2 : o3;
  const int t = threadIdx.x;
  const int k0 = blockIdx.x * 64, n0 = blockIdx.y * 64;
  #pragma unroll
  for (int i = 0; i < 16; ++i) {
    int e = t + i * 256, r = e >> 6, c = e & 63;
    T[c][r] = f2b(W[(size_t)(k0 + r) * D_ + n0 + c]);
  }
  __syncthreads();
  #pragma unroll
  for (int i = 0; i < 16; ++i) {
    int e = t + i * 256, r = e >> 6, c = e & 63;
    Wt[(size_t)(n0 + r) * D_ + k0 + c] = T[r][c];
  }
}

// ---------------------------------------------------------------------------
// MFMA GEMM, m97-style K-loop: BM=BN=128, BK=32, 4 waves 2x2, 4x4 frags/wave.
// Staging: global_load_lds width-16, unpadded [128][32] LDS, XOR-block swizzle.
// MODE 0: PLAIN epilogue -> dense bf16 [4096][1024] per matrix (bias only).
// MODE 2: fp32 [M][N] + bias (final projection), direct stores.
// ---------------------------------------------------------------------------
template <int MODE>
__global__ __launch_bounds__(256) void gemm_mfma(
    const ushort* __restrict__ A0, const ushort* __restrict__ A1,
    const ushort* __restrict__ A2, const ushort* __restrict__ Bt,
    const float* __restrict__ bb0, const float* __restrict__ bb1,
    const float* __restrict__ bb2,
    ushort* __restrict__ oq, ushort* __restrict__ ok, ushort* __restrict__ ov,
    float* __restrict__ oo) {
  __shared__ ushort As[128 * 32];
  __shared__ ushort Bs[128 * 32];
  __shared__ ushort Es[(MODE == 0) ? 9216 : 1];  // [64][144] epilogue scratch

  const int t = threadIdx.x, w = t >> 6, l = t & 63;
  const int m0 = blockIdx.x * 128, n0 = blockIdx.y * 128;
  const int wm = (w >> 1) * 64, wn = (w & 1) * 64;
  const int lm = l & 15, h8 = (l >> 4) * 8, q4 = (l >> 4) * 4;
  const int hb = l >> 4;

  const ushort* A;
  const float* bias;
  int mat = 0;
  if constexpr (MODE == 0) {
    mat = n0 >> 10;
    A = (mat == 0) ? A0 : (mat == 1) ? A1 : A2;
    bias = (mat == 0) ? bb0 : (mat == 1) ? bb1 : bb2;
  } else {
    A = A0; bias = bb0;
  }

  const int srow = w * 32 + (l >> 2);
  const int pb = l & 3;
  const int lb = pb ^ (srow & 3);
  const ushort* gA = A + (size_t)(m0 + srow) * D_ + lb * 8;
  const ushort* gB = Bt + (size_t)(n0 + srow) * D_ + lb * 8;
  ushort* lA = As + w * 1024;
  ushort* lB = Bs + w * 1024;

  f4 acc[4][4];
  #pragma unroll
  for (int i = 0; i < 4; ++i)
    #pragma unroll
    for (int j = 0; j < 4; ++j) acc[i][j] = (f4){0.f, 0.f, 0.f, 0.f};

  for (int k0 = 0; k0 < D_; k0 += 32) {
    async16(gA + k0, lA);
    async16(gA + 16 * D_ + k0, lA + 512);
    async16(gB + k0, lB);
    async16(gB + 16 * D_ + k0, lB + 512);
    __syncthreads();
    s8 af[4], bfr[4];
    #pragma unroll
    for (int mt = 0; mt < 4; ++mt) {
      int ra = wm + mt * 16 + lm;
      af[mt] = *(const s8*)&As[ra * 32 + ((hb ^ (ra & 3)) << 3)];
    }
    #pragma unroll
    for (int nt = 0; nt < 4; ++nt) {
      int rb = wn + nt * 16 + lm;
      bfr[nt] = *(const s8*)&Bs[rb * 32 + ((hb ^ (rb & 3)) << 3)];
    }
    #pragma unroll
    for (int mt = 0; mt < 4; ++mt)
      #pragma unroll
      for (int nt = 0; nt < 4; ++nt)
        acc[mt][nt] = __builtin_amdgcn_mfma_f32_16x16x32_bf16(af[mt], bfr[nt], acc[mt][nt], 0, 0, 0);
    __syncthreads();
  }

  // ---- epilogue ----
  if constexpr (MODE == 2) {
    #pragma unroll
    for (int nt = 0; nt < 4; ++nt) {
      int n = n0 + wn + nt * 16 + lm;
      float bv = bias[n];
      #pragma unroll
      for (int mt = 0; mt < 4; ++mt)
        #pragma unroll
        for (int r = 0; r < 4; ++r)
          oo[(size_t)(m0 + wm + mt * 16 + q4 + r) * D_ + n] = acc[mt][nt][r] + bv;
    }
  } else {
    ushort* dst = (mat == 0) ? oq : (mat == 1) ? ok : ov;
    const int nm0 = n0 & 1023;
    #pragma unroll
    for (int p = 0; p < 2; ++p) {
      if ((w >> 1) == p) {
        #pragma unroll
        for (int nt = 0; nt < 4; ++nt) {
          int col = wn + nt * 16 + lm;
          float bv = bias[nm0 + col];
          #pragma unroll
          for (int mt = 0; mt < 4; ++mt)
            #pragma unroll
            for (int r = 0; r < 4; ++r)
              Es[(mt * 16 + q4 + r) * 144 + col] = f2b(acc[mt][nt][r] + bv);
        }
      }
      __syncthreads();
      #pragma unroll
      for (int i = 0; i < 4; ++i) {
        int e = t + i * 256, row = e >> 4, ch = e & 15;
        *(uint4*)&dst[(size_t)(m0 + p * 64 + row) * D_ + nm0 + ch * 8] =
            *(const uint4*)&Es[row * 144 + ch * 8];
      }
      __syncthreads();
    }
  }
}

// ---------------------------------------------------------------------------
// RoPE + relayout pass (memory-bound). Grid (32 bh, 32 s-tiles), 256 thr.
// ---------------------------------------------------------------------------
__global__ __launch_bounds__(256) void rope_pass(
    const ushort* __restrict__ qtmp, const ushort* __restrict__ ktmp,
    const ushort* __restrict__ vtmp,
    ushort* __restrict__ qfb, ushort* __restrict__ kfb,
    ushort* __restrict__ vtb) {
  __shared__ ushort T[64][72];
  const int t = threadIdx.x;
  const int bh = blockIdx.x, st = blockIdx.y;
  const int b = bh >> 4, h = bh & 15;
  const int s0 = st * 64;
  const int r = t >> 2, c0 = (t & 3) * 16;
  const int s = s0 + r;

  float cs[16], sn[16];
  const float pos = (float)s;
  #pragma unroll
  for (int j = 0; j < 16; ++j) {
    float invf = exp2f(-(float)((c0 + j) & 31) * ROPE_C);
    __sincosf(pos * invf, &sn[j], &cs[j]);
  }

  const size_t src = ((size_t)(b * S_ + s)) * D_ + h * 64 + c0;
  const size_t dstqk = ((size_t)bh * S_ + s) * DK_ + c0;

  #pragma unroll
  for (int tensor = 0; tensor < 2; ++tensor) {
    const ushort* in = tensor ? ktmp : qtmp;
    ushort* out = tensor ? kfb : qfb;
    const float scale = tensor ? 1.f : 0.125f;
    uint4 raw0 = *(const uint4*)&in[src];
    uint4 raw1 = *(const uint4*)&in[src + 8];
    ushort xr[16];
    *(uint4*)&xr[0] = raw0;
    *(uint4*)&xr[8] = raw1;
    float x[16];
    #pragma unroll
    for (int j = 0; j < 16; ++j) x[j] = b2f(xr[j]);
    ushort o[16];
    #pragma unroll
    for (int j = 0; j < 16; j += 2) {
      float e = x[j] * cs[j] - x[j + 1] * sn[j + 1];
      float d = x[j] * sn[j] + x[j + 1] * cs[j + 1];
      o[j] = f2b(e * scale);
      o[j + 1] = f2b(d * scale);
    }
    *(uint4*)&out[dstqk] = *(const uint4*)&o[0];
    *(uint4*)&out[dstqk + 8] = *(const uint4*)&o[8];
  }

  {
    uint4 raw0 = *(const uint4*)&vtmp[src];
    uint4 raw1 = *(const uint4*)&vtmp[src + 8];
    ushort xr[16];
    *(uint4*)&xr[0] = raw0;
    *(uint4*)&xr[8] = raw1;
    #pragma unroll
    for (int j = 0; j < 16; ++j) T[c0 + j][r] = xr[j];
    __syncthreads();
    const size_t dstv = ((size_t)bh * DK_ + r) * S_ + s0 + c0;
    *(uint4*)&vtb[dstv] = *(const uint4*)&T[r][c0];
    *(uint4*)&vtb[dstv + 8] = *(const uint4*)&T[r][c0 + 8];
  }
}

// ---------------------------------------------------------------------------
// MFMA flash attention v3: 32 q-rows per wave (2 subtiles), 2-wave blocks.
// Grid (32 bh, 32 qt), 128 thr. Block = 64 q-rows, K-tile = 64 keys.
// Q fragments held in registers (loaded once from global); K/V frags loaded
// once per nt and reused across both q-subtiles -> K/V LDS reads halve.
// O epilogue staged through Ps (dead after last PV).
// ---------------------------------------------------------------------------
__global__ __launch_bounds__(128) void attn_mfma(const ushort* __restrict__ qf,
                                                 const ushort* __restrict__ kf,
                                                 const ushort* __restrict__ vtf,
                                                 ushort* __restrict__ ctx) {
  __shared__ ushort Ks[64][72], Vts[64][72], Ps[64][72];

  const int t = threadIdx.x, w = t >> 6, l = t & 63;
  const int bh = blockIdx.x, qt = blockIdx.y;
  const int i0 = qt * 64;
  const int lm = l & 15, h8 = (l >> 4) * 8, q4 = (l >> 4) * 4;
  const int qw = w * 32;  // wave q-base within block
  const size_t base = (size_t)bh * S_ * DK_;
  const int b = bh >> 4, h = bh & 15;

  // Q B-fragments direct to registers: [su][dk-half]
  s8 qfr[2][2];
  #pragma unroll
  for (int su = 0; su < 2; ++su) {
    const ushort* qrow = qf + base + (size_t)(i0 + qw + su * 16 + lm) * DK_;
    qfr[su][0] = *(const s8*)&qrow[h8];
    qfr[su][1] = *(const s8*)&qrow[h8 + 32];
  }

  f4 O[2][4];
  #pragma unroll
  for (int su = 0; su < 2; ++su)
    #pragma unroll
    for (int nt = 0; nt < 4; ++nt) O[su][nt] = (f4){0.f, 0.f, 0.f, 0.f};
  float m_[2] = {-1e30f, -1e30f}, l_[2] = {0.f, 0.f};

  for (int jt = 0; jt <= qt; ++jt) {
    const int j0 = jt * 64;
    #pragma unroll
    for (int i = 0; i < 4; ++i) {
      int g = t + i * 128, r = g >> 3, c = (g & 7) * 8;
      *(uint4*)&Ks[r][c] = *(const uint4*)&kf[base + (size_t)(j0 + r) * DK_ + c];
      *(uint4*)&Vts[r][c] = *(const uint4*)&vtf[base + (size_t)r * S_ + j0 + c];
    }
    __syncthreads();

    // S^T = K @ Q^T: K-frags loaded once per nt, reused for both subtiles
    f4 st[2][4];
    #pragma unroll
    for (int nt = 0; nt < 4; ++nt) {
      s8 a0 = *(const s8*)&Ks[nt * 16 + lm][h8];
      s8 a1 = *(const s8*)&Ks[nt * 16 + lm][h8 + 32];
      #pragma unroll
      for (int su = 0; su < 2; ++su) {
        f4 a = (f4){0.f, 0.f, 0.f, 0.f};
        a = __builtin_amdgcn_mfma_f32_16x16x32_bf16(a0, qfr[su][0], a, 0, 0, 0);
        a = __builtin_amdgcn_mfma_f32_16x16x32_bf16(a1, qfr[su][1], a, 0, 0, 0);
        st[su][nt] = a;
      }
    }
    if (jt == qt) {  // causal: key j0+nt16+q4+r vs qrow i0+qw+su16+lm
      #pragma unroll
      for (int su = 0; su < 2; ++su)
        #pragma unroll
        for (int nt = 0; nt < 4; ++nt)
          #pragma unroll
          for (int r = 0; r < 4; ++r)
            if (nt * 16 + q4 + r > qw + su * 16 + lm) st[su][nt][r] = -1e30f;
    }
    // online softmax per subtile (q-row = qw + su*16 + lm)
    float alpha[2];
    #pragma unroll
    for (int su = 0; su < 2; ++su) {
      float pm = st[su][0][0];
      #pragma unroll
      for (int nt = 0; nt < 4; ++nt)
        #pragma unroll
        for (int r = 0; r < 4; ++r) pm = fmaxf(pm, st[su][nt][r]);
      pm = fmaxf(pm, __shfl_xor(pm, 16));
      pm = fmaxf(pm, __shfl_xor(pm, 32));
      float mn = fmaxf(m_[su], pm);
      alpha[su] = exp2f((m_[su] - mn) * LOG2E);
      m_[su] = mn;
      float ps = 0.f;
      #pragma unroll
      for (int nt = 0; nt < 4; ++nt)
        #pragma unroll
        for (int r = 0; r < 4; ++r) {
          float p = exp2f((st[su][nt][r] - mn) * LOG2E);
          st[su][nt][r] = p;
          ps += p;
        }
      ps += __shfl_xor(ps, 16);
      ps += __shfl_xor(ps, 32);
      l_[su] = l_[su] * alpha[su] + ps;
      // P -> LDS A-layout [qrow][key], packed 8B stores
      #pragma unroll
      for (int nt = 0; nt < 4; ++nt) {
        ushort pk[4] = {f2b(st[su][nt][0]), f2b(st[su][nt][1]),
                        f2b(st[su][nt][2]), f2b(st[su][nt][3])};
        *(uint2*)&Ps[qw + su * 16 + lm][nt * 16 + q4] = *(const uint2*)pk;
      }
      // O scale: alpha for rows q4+r (state lives at lanes 0..15)
      float ar[4];
      #pragma unroll
      for (int r = 0; r < 4; ++r) ar[r] = __shfl(alpha[su], q4 + r);
      #pragma unroll
      for (int nt = 0; nt < 4; ++nt)
        #pragma unroll
        for (int r = 0; r < 4; ++r) O[su][nt][r] *= ar[r];
    }
    // PV: V-frags loaded once per nt, reused for both subtiles
    s8 ap[2][2];
    #pragma unroll
    for (int su = 0; su < 2; ++su) {
      ap[su][0] = *(const s8*)&Ps[qw + su * 16 + lm][h8];
      ap[su][1] = *(const s8*)&Ps[qw + su * 16 + lm][h8 + 32];
    }
    #pragma unroll
    for (int nt = 0; nt < 4; ++nt) {
      s8 v0 = *(const s8*)&Vts[nt * 16 + lm][h8];
      s8 v1 = *(const s8*)&Vts[nt * 16 + lm][h8 + 32];
      #pragma unroll
      for (int su = 0; su < 2; ++su) {
        O[su][nt] = __builtin_amdgcn_mfma_f32_16x16x32_bf16(ap[su][0], v0, O[su][nt], 0, 0, 0);
        O[su][nt] = __builtin_amdgcn_mfma_f32_16x16x32_bf16(ap[su][1], v1, O[su][nt], 0, 0, 0);
      }
    }
    __syncthreads();  // before next tile overwrites Ks/Vts
  }

  // epilogue: 1/l via shfl, stage O in Ps (own wave region), 16B stores
  #pragma unroll
  for (int su = 0; su < 2; ++su) {
    float il[4];
    #pragma unroll
    for (int r = 0; r < 4; ++r) il[r] = 1.f / __shfl(l_[su], q4 + r);
    #pragma unroll
    for (int nt = 0; nt < 4; ++nt)
      #pragma unroll
      for (int r = 0; r < 4; ++r)
        Ps[qw + su * 16 + q4 + r][nt * 16 + lm] = f2b(O[su][nt][r] * il[r]);
  }
  __syncthreads();
  #pragma unroll
  for (int i = 0; i < 4; ++i) {
    int g = t + i * 128, row = g >> 3, ch = g & 7;
    int s = i0 + row;
    *(uint4*)&ctx[((size_t)(b * S_ + s)) * D_ + h * 64 + ch * 8] =
        *(const uint4*)&Ps[row][ch * 8];
  }
}

// ---------------------------------------------------------------------------
extern "C" void kernel_launch(void* const* d_in, const int* in_sizes, int n_in,
                              void* d_out, int out_size, void* d_ws, size_t ws_size,
                              hipStream_t stream) {
  const float* q_in = (const float*)d_in[0];
  const float* k_in = (const float*)d_in[1];
  const float* v_in = (const float*)d_in[2];
  const float* Wq = (const float*)d_in[3];
  const float* bq = (const float*)d_in[4];
  const float* Wk = (const float*)d_in[5];
  const float* bk = (const float*)d_in[6];
  const float* Wv = (const float*)d_in[7];
  const float* bv = (const float*)d_in[8];
  const float* Wo = (const float*)d_in[9];
  const float* bo = (const float*)d_in[10];

  const size_t NE = (size_t)B_ * S_ * D_;  // 4,194,304
  ushort* Xbq = (ushort*)d_ws;
  ushort* Xbk = Xbq + NE;
  ushort* Xbv = Xbk + NE;
  ushort* Wtqkv = Xbv + NE;              // [3072][1024] bf16
  ushort* Wto = Wtqkv + 3 * 1024 * 1024;
  ushort* qtmp = Wto + 1024 * 1024;      // dense [4096][1024] bf16
  ushort* ktmp = qtmp + NE;
  ushort* vtmp = ktmp + NE;
  ushort* qfb = vtmp + NE;               // [bh][s][dk]
  ushort* kfb = qfb + NE;
  ushort* vtb = kfb + NE;                // [bh][dk][s]
  ushort* ctxb = qtmp;                   // alias: qtmp dead after rope_pass

  conv_x3<<<6144, 256, 0, stream>>>(q_in, k_in, v_in, Xbq, Xbk, Xbv);
  transpose_w4<<<dim3(16, 16, 4), 256, 0, stream>>>(
      Wq, Wk, Wv, Wo, Wtqkv, Wtqkv + 1024 * 1024, Wtqkv + 2 * 1024 * 1024, Wto);

  gemm_mfma<0><<<dim3(32, 24), 256, 0, stream>>>(
      Xbq, Xbk, Xbv, Wtqkv, bq, bk, bv, qtmp, ktmp, vtmp, nullptr);

  rope_pass<<<dim3(32, 32), 256, 0, stream>>>(qtmp, ktmp, vtmp, qfb, kfb, vtb);

  attn_mfma<<<dim3(32, 32), 128, 0, stream>>>(qfb, kfb, vtb, ctxb);

  gemm_mfma<2><<<dim3(32, 8), 256, 0, stream>>>(
      ctxb, ctxb, ctxb, Wto, bo, bo, bo, nullptr, nullptr, nullptr,
      (float*)d_out);
}